// Round 1
// baseline (3530.943 us; speedup 1.0000x reference)
//
#include <hip/hip_runtime.h>

#define B_ 4
#define N_ 10000
#define E_ 100000
#define H_ 8
#define F_ 32
#define FIN_ 256
#define M_ (B_*N_)    // 40000 rows for node-space GEMMs
#define BE_ (B_*E_)   // 400000 edges total

// ---- ordered-uint encoding for float atomicMax ----
__device__ __forceinline__ unsigned enc_f(float f){
  unsigned u = __float_as_uint(f);
  return (u & 0x80000000u) ? ~u : (u | 0x80000000u);
}
__device__ __forceinline__ float dec_f(unsigned e){
  return (e & 0x80000000u) ? __uint_as_float(e & 0x7FFFFFFFu)
                           : __uint_as_float(~e);
}

// ---------------------------------------------------------------------------
// GEMM: C(M x 256) = A(M x 256) @ W(256 x 256)^T   (out[n,j] = dot(A[n,:], W[j,:]))
// BM=BN=128, BK=16, 256 threads, 8x8 microtile.
// MODE 0: C = A@W^T            (proj)
// MODE 1: out = elu(A@W^T + add1 + add2 + bias)    (final fused epilogue)
// ---------------------------------------------------------------------------
template<int MODE>
__global__ __launch_bounds__(256)
void gemm_k(const float* __restrict__ A, const float* __restrict__ W,
            float* __restrict__ C,
            const float* __restrict__ add1, const float* __restrict__ add2,
            const float* __restrict__ bias)
{
  __shared__ float As[16][132];
  __shared__ float Bs[16][132];
  const int tid  = threadIdx.x;
  const int row0 = blockIdx.x * 128;
  const int col0 = blockIdx.y * 128;
  const int lr   = tid >> 2;        // 0..63 (row within half-tile)
  const int lc4  = (tid & 3) * 4;   // k offset 0/4/8/12
  const int tm   = (tid >> 4) * 8;  // micro row 0..120
  const int tn   = (tid & 15) * 8;  // micro col 0..120

  float acc[8][8];
  #pragma unroll
  for (int i = 0; i < 8; i++)
    #pragma unroll
    for (int j = 0; j < 8; j++) acc[i][j] = 0.f;

  for (int kt = 0; kt < FIN_; kt += 16) {
    #pragma unroll
    for (int half = 0; half < 2; half++) {
      int r = row0 + lr + half * 64;
      float4 v = make_float4(0.f, 0.f, 0.f, 0.f);
      if (r < M_) v = *(const float4*)&A[(size_t)r * FIN_ + kt + lc4];
      As[lc4+0][lr + half*64] = v.x;
      As[lc4+1][lr + half*64] = v.y;
      As[lc4+2][lr + half*64] = v.z;
      As[lc4+3][lr + half*64] = v.w;

      int j = col0 + lr + half * 64;   // always < 256
      float4 w = *(const float4*)&W[(size_t)j * FIN_ + kt + lc4];
      Bs[lc4+0][lr + half*64] = w.x;
      Bs[lc4+1][lr + half*64] = w.y;
      Bs[lc4+2][lr + half*64] = w.z;
      Bs[lc4+3][lr + half*64] = w.w;
    }
    __syncthreads();
    #pragma unroll
    for (int k = 0; k < 16; k++) {
      float a[8], b[8];
      *(float4*)&a[0] = *(const float4*)&As[k][tm];
      *(float4*)&a[4] = *(const float4*)&As[k][tm+4];
      *(float4*)&b[0] = *(const float4*)&Bs[k][tn];
      *(float4*)&b[4] = *(const float4*)&Bs[k][tn+4];
      #pragma unroll
      for (int i = 0; i < 8; i++)
        #pragma unroll
        for (int j = 0; j < 8; j++)
          acc[i][j] = fmaf(a[i], b[j], acc[i][j]);
    }
    __syncthreads();
  }

  #pragma unroll
  for (int i = 0; i < 8; i++) {
    int r = row0 + tm + i;
    if (r >= M_) continue;
    if (MODE == 0) {
      *(float4*)&C[(size_t)r * FIN_ + col0 + tn]     = *(float4*)&acc[i][0];
      *(float4*)&C[(size_t)r * FIN_ + col0 + tn + 4] = *(float4*)&acc[i][4];
    } else {
      #pragma unroll
      for (int j = 0; j < 8; j++) {
        int c = col0 + tn + j;
        float v = acc[i][j] + add1[(size_t)r * FIN_ + c]
                            + add2[(size_t)r * FIN_ + c] + bias[c];
        C[(size_t)r * FIN_ + c] = (v > 0.f) ? v : expm1f(v);
      }
    }
  }
}

// ---------------------------------------------------------------------------
// Per-(b,n,h) attention scores: s_src/s_trg = sum_f proj[...,h,f]*a_{src,trg}[h,f]
// ---------------------------------------------------------------------------
__global__ void node_scores_k(const float* __restrict__ proj,
                              const float* __restrict__ a_src,
                              const float* __restrict__ a_trg,
                              float* __restrict__ s_src,
                              float* __restrict__ s_trg)
{
  int i = blockIdx.x * 256 + threadIdx.x;   // (b*N+n)*8 + h
  if (i >= M_ * H_) return;
  int h = i & 7;
  const float* p  = proj  + (size_t)i * F_;   // == (b*N+n)*256 + h*32
  const float* as = a_src + h * F_;
  const float* at = a_trg + h * F_;
  float ss = 0.f, st = 0.f;
  #pragma unroll
  for (int f = 0; f < F_; f += 4) {
    float4 pv = *(const float4*)&p[f];
    float4 av = *(const float4*)&as[f];
    float4 tv = *(const float4*)&at[f];
    ss += pv.x*av.x + pv.y*av.y + pv.z*av.z + pv.w*av.w;
    st += pv.x*tv.x + pv.y*tv.y + pv.z*tv.z + pv.w*tv.w;
  }
  s_src[i] = ss;
  s_trg[i] = st;
}

// ---------------------------------------------------------------------------
// Per-edge leaky_relu scores + per-batch global max (encoded atomicMax)
// ---------------------------------------------------------------------------
__global__ void edge_scores_k(const int* __restrict__ ei,
                              const float* __restrict__ s_src,
                              const float* __restrict__ s_trg,
                              float* __restrict__ s_e,
                              unsigned* __restrict__ bmax)
{
  __shared__ unsigned smax[B_];
  if (threadIdx.x < B_) smax[threadIdx.x] = 0u;
  __syncthreads();

  int i = blockIdx.x * 256 + threadIdx.x;
  int b = 0;
  float lmax = -3.4e38f;
  if (i < BE_) {
    b = i / E_;
    int e = i - b * E_;
    int src = ei[(size_t)b * 2 * E_ + e];
    int trg = ei[(size_t)b * 2 * E_ + E_ + e];
    const float* ps = s_src + ((size_t)b * N_ + src) * H_;
    const float* pt = s_trg + ((size_t)b * N_ + trg) * H_;
    float4 s0 = *(const float4*)ps,     s1 = *(const float4*)(ps + 4);
    float4 t0 = *(const float4*)pt,     t1 = *(const float4*)(pt + 4);
    float v[8] = { s0.x+t0.x, s0.y+t0.y, s0.z+t0.z, s0.w+t0.w,
                   s1.x+t1.x, s1.y+t1.y, s1.z+t1.z, s1.w+t1.w };
    #pragma unroll
    for (int h = 0; h < 8; h++) {
      v[h] = (v[h] > 0.f) ? v[h] : 0.2f * v[h];
      lmax = fmaxf(lmax, v[h]);
    }
    *(float4*)&s_e[(size_t)i * 8]     = make_float4(v[0], v[1], v[2], v[3]);
    *(float4*)&s_e[(size_t)i * 8 + 4] = make_float4(v[4], v[5], v[6], v[7]);
    atomicMax(&smax[b], enc_f(lmax));
  }
  __syncthreads();
  if (threadIdx.x < B_ && smax[threadIdx.x] != 0u)
    atomicMax(&bmax[threadIdx.x], smax[threadIdx.x]);
}

// ---------------------------------------------------------------------------
// exp(s - batch_max), in-place; seg-sum denominators via atomics
// ---------------------------------------------------------------------------
__global__ void exp_denom_k(const int* __restrict__ ei,
                            const unsigned* __restrict__ bmax,
                            float* __restrict__ s_e,
                            float* __restrict__ denom)
{
  int i = blockIdx.x * 256 + threadIdx.x;
  if (i >= BE_) return;
  int b = i / E_;
  int e = i - b * E_;
  int trg = ei[(size_t)b * 2 * E_ + E_ + e];
  float m = dec_f(bmax[b]);
  float* se = s_e + (size_t)i * 8;
  float ex[8];
  #pragma unroll
  for (int h = 0; h < 8; h++) ex[h] = expf(se[h] - m);
  *(float4*)&se[0] = make_float4(ex[0], ex[1], ex[2], ex[3]);
  *(float4*)&se[4] = make_float4(ex[4], ex[5], ex[6], ex[7]);
  float* dn = denom + ((size_t)b * N_ + trg) * H_;
  #pragma unroll
  for (int h = 0; h < 8; h++) atomicAdd(&dn[h], ex[h]);
}

// ---------------------------------------------------------------------------
// rel aggregate: rel_agg[b,trg,:] += rel[b,e,:]   (wave per edge, coalesced)
// ---------------------------------------------------------------------------
__global__ __launch_bounds__(256)
void rel_agg_k(const int* __restrict__ ei,
               const float* __restrict__ rel,
               float* __restrict__ rel_agg)
{
  int w    = (blockIdx.x << 2) | (threadIdx.x >> 6);  // edge id
  int lane = threadIdx.x & 63;
  if (w >= BE_) return;
  int b = w / E_;
  int e = w - b * E_;
  int trg = ei[(size_t)b * 2 * E_ + E_ + e];
  float4 v = *(const float4*)&rel[((size_t)b * E_ + e) * FIN_ + lane * 4];
  float* dst = rel_agg + ((size_t)b * N_ + trg) * FIN_ + lane * 4;
  atomicAdd(dst + 0, v.x);
  atomicAdd(dst + 1, v.y);
  atomicAdd(dst + 2, v.z);
  atomicAdd(dst + 3, v.w);
}

// ---------------------------------------------------------------------------
// message: out_acc[b,trg,:] += proj[b,src,:] * att[h]   (wave per edge)
// ---------------------------------------------------------------------------
__global__ __launch_bounds__(256)
void message_k(const int* __restrict__ ei,
               const float* __restrict__ exp_s,
               const float* __restrict__ denom,
               const float* __restrict__ proj,
               float* __restrict__ out_acc)
{
  int w    = (blockIdx.x << 2) | (threadIdx.x >> 6);
  int lane = threadIdx.x & 63;
  if (w >= BE_) return;
  int b = w / E_;
  int e = w - b * E_;
  int src = ei[(size_t)b * 2 * E_ + e];
  int trg = ei[(size_t)b * 2 * E_ + E_ + e];
  int h = lane >> 3;
  float att = exp_s[(size_t)w * 8 + h]
            / (denom[((size_t)b * N_ + trg) * H_ + h] + 1e-16f);
  float4 p = *(const float4*)&proj[((size_t)b * N_ + src) * FIN_ + lane * 4];
  float* dst = out_acc + ((size_t)b * N_ + trg) * FIN_ + lane * 4;
  atomicAdd(dst + 0, p.x * att);
  atomicAdd(dst + 1, p.y * att);
  atomicAdd(dst + 2, p.z * att);
  atomicAdd(dst + 3, p.w * att);
}

// ---------------------------------------------------------------------------
extern "C" void kernel_launch(void* const* d_in, const int* in_sizes, int n_in,
                              void* d_out, int out_size, void* d_ws, size_t ws_size,
                              hipStream_t stream)
{
  const float* x     = (const float*)d_in[0];
  const int*   ei    = (const int*)  d_in[1];
  const float* rel   = (const float*)d_in[2];
  const float* W     = (const float*)d_in[3];
  const float* a_src = (const float*)d_in[4];
  const float* a_trg = (const float*)d_in[5];
  const float* bias  = (const float*)d_in[6];
  float* out = (float*)d_out;

  float* ws      = (float*)d_ws;
  float* proj    = ws;                                  // M*FIN
  float* s_src   = proj    + (size_t)M_ * FIN_;         // M*H
  float* s_trg   = s_src   + (size_t)M_ * H_;           // M*H
  float* s_e     = s_trg   + (size_t)M_ * H_;           // BE*H (becomes exp_s)
  float* denom   = s_e     + (size_t)BE_ * H_;          // M*H   -- zero region start
  float* rel_agg = denom   + (size_t)M_ * H_;           // M*FIN
  float* out_acc = rel_agg + (size_t)M_ * FIN_;         // M*FIN
  unsigned* bmax = (unsigned*)(out_acc + (size_t)M_ * FIN_); // B

  size_t zero_bytes = ((size_t)M_ * H_ + 2 * (size_t)M_ * FIN_) * sizeof(float)
                    + B_ * sizeof(unsigned);
  hipMemsetAsync(denom, 0, zero_bytes, stream);

  gemm_k<0><<<dim3(313, 2), 256, 0, stream>>>(x, W, proj, nullptr, nullptr, nullptr);

  node_scores_k<<<(M_ * H_ + 255) / 256, 256, 0, stream>>>(proj, a_src, a_trg, s_src, s_trg);

  edge_scores_k<<<(BE_ + 255) / 256, 256, 0, stream>>>(ei, s_src, s_trg, s_e, bmax);

  exp_denom_k<<<(BE_ + 255) / 256, 256, 0, stream>>>(ei, bmax, s_e, denom);

  rel_agg_k<<<BE_ / 4, 256, 0, stream>>>(ei, rel, rel_agg);

  message_k<<<BE_ / 4, 256, 0, stream>>>(ei, s_e, denom, proj, out_acc);

  gemm_k<1><<<dim3(313, 2), 256, 0, stream>>>(rel_agg, W, out, out_acc, x, bias);
}

// Round 2
// 897.117 us; speedup vs baseline: 3.9359x; 3.9359x over previous
//
#include <hip/hip_runtime.h>

#define B_ 4
#define N_ 10000
#define E_ 100000
#define H_ 8
#define F_ 32
#define FIN_ 256
#define M_ (B_*N_)    // 40000 node rows
#define BE_ (B_*E_)   // 400000 edges total

// ---- ordered-uint encoding for float atomicMax ----
__device__ __forceinline__ unsigned enc_f(float f){
  unsigned u = __float_as_uint(f);
  return (u & 0x80000000u) ? ~u : (u | 0x80000000u);
}
__device__ __forceinline__ float dec_f(unsigned e){
  return (e & 0x80000000u) ? __uint_as_float(e & 0x7FFFFFFFu)
                           : __uint_as_float(~e);
}

// ---------------------------------------------------------------------------
// GEMM: C(M x 256) = A(M x 256) @ W(256 x 256)^T
// MODE 0: C = A@W^T            (proj)
// MODE 1: out = elu(A@W^T + add1 + add2 + bias)
// ---------------------------------------------------------------------------
template<int MODE>
__global__ __launch_bounds__(256)
void gemm_k(const float* __restrict__ A, const float* __restrict__ W,
            float* __restrict__ C,
            const float* __restrict__ add1, const float* __restrict__ add2,
            const float* __restrict__ bias)
{
  __shared__ float As[16][132];
  __shared__ float Bs[16][132];
  const int tid  = threadIdx.x;
  const int row0 = blockIdx.x * 128;
  const int col0 = blockIdx.y * 128;
  const int lr   = tid >> 2;
  const int lc4  = (tid & 3) * 4;
  const int tm   = (tid >> 4) * 8;
  const int tn   = (tid & 15) * 8;

  float acc[8][8];
  #pragma unroll
  for (int i = 0; i < 8; i++)
    #pragma unroll
    for (int j = 0; j < 8; j++) acc[i][j] = 0.f;

  for (int kt = 0; kt < FIN_; kt += 16) {
    #pragma unroll
    for (int half = 0; half < 2; half++) {
      int r = row0 + lr + half * 64;
      float4 v = make_float4(0.f, 0.f, 0.f, 0.f);
      if (r < M_) v = *(const float4*)&A[(size_t)r * FIN_ + kt + lc4];
      As[lc4+0][lr + half*64] = v.x;
      As[lc4+1][lr + half*64] = v.y;
      As[lc4+2][lr + half*64] = v.z;
      As[lc4+3][lr + half*64] = v.w;

      int j = col0 + lr + half * 64;
      float4 w = *(const float4*)&W[(size_t)j * FIN_ + kt + lc4];
      Bs[lc4+0][lr + half*64] = w.x;
      Bs[lc4+1][lr + half*64] = w.y;
      Bs[lc4+2][lr + half*64] = w.z;
      Bs[lc4+3][lr + half*64] = w.w;
    }
    __syncthreads();
    #pragma unroll
    for (int k = 0; k < 16; k++) {
      float a[8], b[8];
      *(float4*)&a[0] = *(const float4*)&As[k][tm];
      *(float4*)&a[4] = *(const float4*)&As[k][tm+4];
      *(float4*)&b[0] = *(const float4*)&Bs[k][tn];
      *(float4*)&b[4] = *(const float4*)&Bs[k][tn+4];
      #pragma unroll
      for (int i = 0; i < 8; i++)
        #pragma unroll
        for (int j = 0; j < 8; j++)
          acc[i][j] = fmaf(a[i], b[j], acc[i][j]);
    }
    __syncthreads();
  }

  #pragma unroll
  for (int i = 0; i < 8; i++) {
    int r = row0 + tm + i;
    if (r >= M_) continue;
    if (MODE == 0) {
      *(float4*)&C[(size_t)r * FIN_ + col0 + tn]     = *(float4*)&acc[i][0];
      *(float4*)&C[(size_t)r * FIN_ + col0 + tn + 4] = *(float4*)&acc[i][4];
    } else {
      #pragma unroll
      for (int j = 0; j < 8; j++) {
        int c = col0 + tn + j;
        float v = acc[i][j] + add1[(size_t)r * FIN_ + c]
                            + add2[(size_t)r * FIN_ + c] + bias[c];
        C[(size_t)r * FIN_ + c] = (v > 0.f) ? v : expm1f(v);
      }
    }
  }
}

// ---------------------------------------------------------------------------
// Per-(b,n,h) attention scores
// ---------------------------------------------------------------------------
__global__ void node_scores_k(const float* __restrict__ proj,
                              const float* __restrict__ a_src,
                              const float* __restrict__ a_trg,
                              float* __restrict__ s_src,
                              float* __restrict__ s_trg)
{
  int i = blockIdx.x * 256 + threadIdx.x;
  if (i >= M_ * H_) return;
  int h = i & 7;
  const float* p  = proj  + (size_t)i * F_;
  const float* as = a_src + h * F_;
  const float* at = a_trg + h * F_;
  float ss = 0.f, st = 0.f;
  #pragma unroll
  for (int f = 0; f < F_; f += 4) {
    float4 pv = *(const float4*)&p[f];
    float4 av = *(const float4*)&as[f];
    float4 tv = *(const float4*)&at[f];
    ss += pv.x*av.x + pv.y*av.y + pv.z*av.z + pv.w*av.w;
    st += pv.x*tv.x + pv.y*tv.y + pv.z*tv.z + pv.w*tv.w;
  }
  s_src[i] = ss;
  s_trg[i] = st;
}

// ---------------------------------------------------------------------------
// Per-edge leaky_relu scores + per-batch max (encoded atomicMax)
// ---------------------------------------------------------------------------
__global__ void edge_scores_k(const int* __restrict__ ei,
                              const float* __restrict__ s_src,
                              const float* __restrict__ s_trg,
                              float* __restrict__ s_e,
                              unsigned* __restrict__ bmax)
{
  __shared__ unsigned smax[B_];
  if (threadIdx.x < B_) smax[threadIdx.x] = 0u;
  __syncthreads();

  int i = blockIdx.x * 256 + threadIdx.x;
  int b = 0;
  if (i < BE_) {
    b = i / E_;
    int e = i - b * E_;
    int src = ei[(size_t)b * 2 * E_ + e];
    int trg = ei[(size_t)b * 2 * E_ + E_ + e];
    const float* ps = s_src + ((size_t)b * N_ + src) * H_;
    const float* pt = s_trg + ((size_t)b * N_ + trg) * H_;
    float4 s0 = *(const float4*)ps,     s1 = *(const float4*)(ps + 4);
    float4 t0 = *(const float4*)pt,     t1 = *(const float4*)(pt + 4);
    float v[8] = { s0.x+t0.x, s0.y+t0.y, s0.z+t0.z, s0.w+t0.w,
                   s1.x+t1.x, s1.y+t1.y, s1.z+t1.z, s1.w+t1.w };
    float lmax = -3.4e38f;
    #pragma unroll
    for (int h = 0; h < 8; h++) {
      v[h] = (v[h] > 0.f) ? v[h] : 0.2f * v[h];
      lmax = fmaxf(lmax, v[h]);
    }
    *(float4*)&s_e[(size_t)i * 8]     = make_float4(v[0], v[1], v[2], v[3]);
    *(float4*)&s_e[(size_t)i * 8 + 4] = make_float4(v[4], v[5], v[6], v[7]);
    atomicMax(&smax[b], enc_f(lmax));
  }
  __syncthreads();
  if (threadIdx.x < B_ && smax[threadIdx.x] != 0u)
    atomicMax(&bmax[threadIdx.x], smax[threadIdx.x]);
}

// ---------------------------------------------------------------------------
// CSR build: count -> scan -> scatter
// ---------------------------------------------------------------------------
__global__ void count_k(const int* __restrict__ ei, int* __restrict__ cnt)
{
  int i = blockIdx.x * 256 + threadIdx.x;
  if (i >= BE_) return;
  int b = i / E_, e = i - b * E_;
  int trg = ei[(size_t)b * 2 * E_ + E_ + e];
  atomicAdd(&cnt[b * N_ + trg], 1);
}

// one block per batch; exclusive scan of 10000 counts -> global slot offsets
__global__ __launch_bounds__(1024)
void scan_k(const int* __restrict__ cnt, int* __restrict__ offs,
            int* __restrict__ cursor)
{
  int b = blockIdx.x;
  __shared__ int sdata[1024];
  __shared__ int carry;
  if (threadIdx.x == 0) carry = 0;
  __syncthreads();
  for (int base = 0; base < N_; base += 1024) {
    int idx = base + threadIdx.x;
    int v = (idx < N_) ? cnt[b * N_ + idx] : 0;
    sdata[threadIdx.x] = v;
    __syncthreads();
    #pragma unroll
    for (int off = 1; off < 1024; off <<= 1) {
      int t = (threadIdx.x >= off) ? sdata[threadIdx.x - off] : 0;
      __syncthreads();
      sdata[threadIdx.x] += t;
      __syncthreads();
    }
    int incl = sdata[threadIdx.x];
    int excl = incl - v + carry;
    if (idx < N_) {
      offs[b * N_ + idx]   = b * E_ + excl;
      cursor[b * N_ + idx] = b * E_ + excl;
    }
    __syncthreads();
    if (threadIdx.x == 1023) carry += incl;
    __syncthreads();
  }
}

__global__ void scatter_k(const int* __restrict__ ei, int* __restrict__ cursor,
                          int2* __restrict__ rec)
{
  int i = blockIdx.x * 256 + threadIdx.x;
  if (i >= BE_) return;
  int b = i / E_, e = i - b * E_;
  int src = ei[(size_t)b * 2 * E_ + e];
  int trg = ei[(size_t)b * 2 * E_ + E_ + e];
  int pos = atomicAdd(&cursor[b * N_ + trg], 1);
  rec[pos] = make_int2(src, i);   // i = global edge id b*E+e
}

// ---------------------------------------------------------------------------
// Fused gather-aggregation: one wave per node.
//   out_acc[n,:] = (sum_e exp(s_e - m) * proj[src_e,:]) / (sum_e exp + 1e-16)
//   rel_agg[n,:] =  sum_e rel[e,:]
// Each output row written exactly once — no atomics.
// ---------------------------------------------------------------------------
__global__ __launch_bounds__(256)
void agg_k(const int2* __restrict__ rec, const int* __restrict__ offs,
           const int* __restrict__ cnt, const float* __restrict__ s_e,
           const unsigned* __restrict__ bmax,
           const float* __restrict__ proj, const float* __restrict__ rel,
           float* __restrict__ rel_agg, float* __restrict__ out_acc)
{
  int node = blockIdx.x * 4 + (threadIdx.x >> 6);   // global node id b*N+n
  if (node >= M_) return;
  int lane = threadIdx.x & 63;
  int b = node / N_;
  float m = dec_f(bmax[b]);
  int start = offs[node];
  int num   = cnt[node];
  int h = lane >> 3;                                 // head for this lane's cols

  float4 pacc = make_float4(0.f, 0.f, 0.f, 0.f);
  float4 racc = make_float4(0.f, 0.f, 0.f, 0.f);
  float  dacc = 0.f;

  for (int i = 0; i < num; i++) {
    int2 r = rec[start + i];
    int src = r.x;        // per-batch node index
    int ge  = r.y;        // global edge index
    float ex = expf(s_e[(size_t)ge * 8 + h] - m);
    dacc += ex;
    float4 p = *(const float4*)&proj[((size_t)b * N_ + src) * FIN_ + lane * 4];
    pacc.x += p.x * ex; pacc.y += p.y * ex;
    pacc.z += p.z * ex; pacc.w += p.w * ex;
    float4 rv = *(const float4*)&rel[(size_t)ge * FIN_ + lane * 4];
    racc.x += rv.x; racc.y += rv.y; racc.z += rv.z; racc.w += rv.w;
  }

  float inv = 1.f / (dacc + 1e-16f);
  pacc.x *= inv; pacc.y *= inv; pacc.z *= inv; pacc.w *= inv;
  *(float4*)&out_acc[(size_t)node * FIN_ + lane * 4] = pacc;
  *(float4*)&rel_agg[(size_t)node * FIN_ + lane * 4] = racc;
}

// ---------------------------------------------------------------------------
extern "C" void kernel_launch(void* const* d_in, const int* in_sizes, int n_in,
                              void* d_out, int out_size, void* d_ws, size_t ws_size,
                              hipStream_t stream)
{
  const float* x     = (const float*)d_in[0];
  const int*   ei    = (const int*)  d_in[1];
  const float* rel   = (const float*)d_in[2];
  const float* W     = (const float*)d_in[3];
  const float* a_src = (const float*)d_in[4];
  const float* a_trg = (const float*)d_in[5];
  const float* bias  = (const float*)d_in[6];
  float* out = (float*)d_out;

  float* ws = (float*)d_ws;
  size_t o = 0;
  float* proj    = ws + o; o += (size_t)M_ * FIN_;
  float* s_src   = ws + o; o += (size_t)M_ * H_;
  float* s_trg   = ws + o; o += (size_t)M_ * H_;
  float* s_e     = ws + o; o += (size_t)BE_ * H_;
  float* rel_agg = ws + o; o += (size_t)M_ * FIN_;
  float* out_acc = ws + o; o += (size_t)M_ * FIN_;
  int* cnt       = (int*)(ws + o);      o += M_;
  unsigned* bmax = (unsigned*)(ws + o); o += B_;
  int* offs      = (int*)(ws + o);      o += M_;
  int* cursor    = (int*)(ws + o);      o += M_;
  if (o & 1) o++;
  int2* rec      = (int2*)(ws + o);     o += (size_t)2 * BE_;

  // zero cnt + bmax (adjacent)
  hipMemsetAsync(cnt, 0, (M_ + B_) * sizeof(int), stream);

  gemm_k<0><<<dim3(313, 2), 256, 0, stream>>>(x, W, proj, nullptr, nullptr, nullptr);

  node_scores_k<<<(M_ * H_ + 255) / 256, 256, 0, stream>>>(proj, a_src, a_trg, s_src, s_trg);

  edge_scores_k<<<(BE_ + 255) / 256, 256, 0, stream>>>(ei, s_src, s_trg, s_e, bmax);

  count_k<<<(BE_ + 255) / 256, 256, 0, stream>>>(ei, cnt);
  scan_k<<<B_, 1024, 0, stream>>>(cnt, offs, cursor);
  scatter_k<<<(BE_ + 255) / 256, 256, 0, stream>>>(ei, cursor, rec);

  agg_k<<<M_ / 4, 256, 0, stream>>>(rec, offs, cnt, s_e, bmax, proj, rel,
                                    rel_agg, out_acc);

  gemm_k<1><<<dim3(313, 2), 256, 0, stream>>>(rel_agg, W, out, out_acc, x, bias);
}

// Round 3
// 889.292 us; speedup vs baseline: 3.9705x; 1.0088x over previous
//
#include <hip/hip_runtime.h>

#define B_ 4
#define N_ 10000
#define E_ 100000
#define H_ 8
#define F_ 32
#define FIN_ 256
#define M_ (B_*N_)    // 40000 node rows
#define BE_ (B_*E_)   // 400000 edges total

typedef float f4 __attribute__((ext_vector_type(4)));

// ---- ordered-uint encoding for float atomicMax ----
__device__ __forceinline__ unsigned enc_f(float f){
  unsigned u = __float_as_uint(f);
  return (u & 0x80000000u) ? ~u : (u | 0x80000000u);
}
__device__ __forceinline__ float dec_f(unsigned e){
  return (e & 0x80000000u) ? __uint_as_float(e & 0x7FFFFFFFu)
                           : __uint_as_float(~e);
}

// LDS column swizzle: spread 8-float chunks so b128 reads are <=2-way (free)
#define SW(c) ((c) + (((c) >> 5) << 1))

// ---------------------------------------------------------------------------
// GEMM: C(M x 256) = A(M x 256) @ W(256 x 256)^T
// MODE 0: C = A@W^T            (proj)
// MODE 1: out = elu(A@W^T + add1 + add2 + bias)
// ---------------------------------------------------------------------------
template<int MODE>
__global__ __launch_bounds__(256)
void gemm_k(const float* __restrict__ A, const float* __restrict__ W,
            float* __restrict__ C,
            const float* __restrict__ add1, const float* __restrict__ add2,
            const float* __restrict__ bias)
{
  __shared__ float As[16][136];
  __shared__ float Bs[16][136];
  const int tid  = threadIdx.x;
  const int row0 = blockIdx.x * 128;
  const int col0 = blockIdx.y * 128;
  const int lr   = tid >> 2;
  const int lc4  = (tid & 3) * 4;
  const int tm   = (tid >> 4) * 8;
  const int tn   = (tid & 15) * 8;

  float acc[8][8];
  #pragma unroll
  for (int i = 0; i < 8; i++)
    #pragma unroll
    for (int j = 0; j < 8; j++) acc[i][j] = 0.f;

  for (int kt = 0; kt < FIN_; kt += 16) {
    #pragma unroll
    for (int half = 0; half < 2; half++) {
      int col = lr + half * 64;
      int r = row0 + col;
      float4 v = make_float4(0.f, 0.f, 0.f, 0.f);
      if (r < M_) v = *(const float4*)&A[(size_t)r * FIN_ + kt + lc4];
      As[lc4+0][SW(col)] = v.x;
      As[lc4+1][SW(col)] = v.y;
      As[lc4+2][SW(col)] = v.z;
      As[lc4+3][SW(col)] = v.w;

      int j = col0 + col;
      float4 w = *(const float4*)&W[(size_t)j * FIN_ + kt + lc4];
      Bs[lc4+0][SW(col)] = w.x;
      Bs[lc4+1][SW(col)] = w.y;
      Bs[lc4+2][SW(col)] = w.z;
      Bs[lc4+3][SW(col)] = w.w;
    }
    __syncthreads();
    #pragma unroll
    for (int k = 0; k < 16; k++) {
      float a[8], b[8];
      *(float4*)&a[0] = *(const float4*)&As[k][SW(tm)];
      *(float4*)&a[4] = *(const float4*)&As[k][SW(tm+4)];
      *(float4*)&b[0] = *(const float4*)&Bs[k][SW(tn)];
      *(float4*)&b[4] = *(const float4*)&Bs[k][SW(tn+4)];
      #pragma unroll
      for (int i = 0; i < 8; i++)
        #pragma unroll
        for (int j = 0; j < 8; j++)
          acc[i][j] = fmaf(a[i], b[j], acc[i][j]);
    }
    __syncthreads();
  }

  #pragma unroll
  for (int i = 0; i < 8; i++) {
    int r = row0 + tm + i;
    if (r >= M_) continue;
    if (MODE == 0) {
      *(float4*)&C[(size_t)r * FIN_ + col0 + tn]     = *(float4*)&acc[i][0];
      *(float4*)&C[(size_t)r * FIN_ + col0 + tn + 4] = *(float4*)&acc[i][4];
    } else {
      const size_t ro = (size_t)r * FIN_ + col0 + tn;
      #pragma unroll
      for (int q = 0; q < 2; q++) {
        float4 a1 = *(const float4*)&add1[ro + q*4];
        float4 a2 = *(const float4*)&add2[ro + q*4];
        float4 bb = *(const float4*)&bias[col0 + tn + q*4];
        float vv[4] = { acc[i][q*4+0] + a1.x + a2.x + bb.x,
                        acc[i][q*4+1] + a1.y + a2.y + bb.y,
                        acc[i][q*4+2] + a1.z + a2.z + bb.z,
                        acc[i][q*4+3] + a1.w + a2.w + bb.w };
        float4 o;
        o.x = (vv[0] > 0.f) ? vv[0] : expm1f(vv[0]);
        o.y = (vv[1] > 0.f) ? vv[1] : expm1f(vv[1]);
        o.z = (vv[2] > 0.f) ? vv[2] : expm1f(vv[2]);
        o.w = (vv[3] > 0.f) ? vv[3] : expm1f(vv[3]);
        *(float4*)&C[ro + q*4] = o;
      }
    }
  }
}

// ---------------------------------------------------------------------------
// Per-(b,n,h) attention scores
// ---------------------------------------------------------------------------
__global__ void node_scores_k(const float* __restrict__ proj,
                              const float* __restrict__ a_src,
                              const float* __restrict__ a_trg,
                              float* __restrict__ s_src,
                              float* __restrict__ s_trg)
{
  int i = blockIdx.x * 256 + threadIdx.x;
  if (i >= M_ * H_) return;
  int h = i & 7;
  const float* p  = proj  + (size_t)i * F_;
  const float* as = a_src + h * F_;
  const float* at = a_trg + h * F_;
  float ss = 0.f, st = 0.f;
  #pragma unroll
  for (int f = 0; f < F_; f += 4) {
    float4 pv = *(const float4*)&p[f];
    float4 av = *(const float4*)&as[f];
    float4 tv = *(const float4*)&at[f];
    ss += pv.x*av.x + pv.y*av.y + pv.z*av.z + pv.w*av.w;
    st += pv.x*tv.x + pv.y*tv.y + pv.z*tv.z + pv.w*tv.w;
  }
  s_src[i] = ss;
  s_trg[i] = st;
}

// ---------------------------------------------------------------------------
// Per-edge leaky_relu scores + per-batch max + per-target count (fused)
// ---------------------------------------------------------------------------
__global__ void edge_scores_k(const int* __restrict__ ei,
                              const float* __restrict__ s_src,
                              const float* __restrict__ s_trg,
                              float* __restrict__ s_e,
                              unsigned* __restrict__ bmax,
                              int* __restrict__ cnt)
{
  __shared__ unsigned smax[B_];
  if (threadIdx.x < B_) smax[threadIdx.x] = 0u;
  __syncthreads();

  int i = blockIdx.x * 256 + threadIdx.x;
  if (i < BE_) {
    int b = i / E_;
    int e = i - b * E_;
    int src = ei[(size_t)b * 2 * E_ + e];
    int trg = ei[(size_t)b * 2 * E_ + E_ + e];
    atomicAdd(&cnt[b * N_ + trg], 1);
    const float* ps = s_src + ((size_t)b * N_ + src) * H_;
    const float* pt = s_trg + ((size_t)b * N_ + trg) * H_;
    float4 s0 = *(const float4*)ps,     s1 = *(const float4*)(ps + 4);
    float4 t0 = *(const float4*)pt,     t1 = *(const float4*)(pt + 4);
    float v[8] = { s0.x+t0.x, s0.y+t0.y, s0.z+t0.z, s0.w+t0.w,
                   s1.x+t1.x, s1.y+t1.y, s1.z+t1.z, s1.w+t1.w };
    float lmax = -3.4e38f;
    #pragma unroll
    for (int h = 0; h < 8; h++) {
      v[h] = (v[h] > 0.f) ? v[h] : 0.2f * v[h];
      lmax = fmaxf(lmax, v[h]);
    }
    *(float4*)&s_e[(size_t)i * 8]     = make_float4(v[0], v[1], v[2], v[3]);
    *(float4*)&s_e[(size_t)i * 8 + 4] = make_float4(v[4], v[5], v[6], v[7]);
    atomicMax(&smax[b], enc_f(lmax));
  }
  __syncthreads();
  if (threadIdx.x < B_ && smax[threadIdx.x] != 0u)
    atomicMax(&bmax[threadIdx.x], smax[threadIdx.x]);
}

// ---------------------------------------------------------------------------
// Single-block exclusive scan over all 40000 counts.
// Per-batch totals are exactly E_, so the global exclusive prefix IS
// b*E_ + within-batch offset.
// ---------------------------------------------------------------------------
__global__ __launch_bounds__(1024)
void scan_k(const int* __restrict__ cnt, int* __restrict__ offs,
            int* __restrict__ cursor)
{
  const int PER = 40;                   // 1024*40 >= 40000
  int t = threadIdx.x;
  int lane = t & 63, wid = t >> 6;      // 16 waves
  int base = t * PER;

  int pre[PER];
  int s = 0;
  #pragma unroll
  for (int i = 0; i < PER; i++) {
    int idx = base + i;
    int v = (idx < M_) ? cnt[idx] : 0;
    pre[i] = s; s += v;
  }
  // wave-inclusive scan of per-thread totals
  int incl = s;
  #pragma unroll
  for (int off = 1; off < 64; off <<= 1) {
    int n = __shfl_up(incl, off);
    if (lane >= off) incl += n;
  }
  __shared__ int wtot[16];
  if (lane == 63) wtot[wid] = incl;
  __syncthreads();
  int wbase = 0;
  for (int w = 0; w < wid; w++) wbase += wtot[w];
  int tp = wbase + (incl - s);          // exclusive prefix of this thread
  #pragma unroll
  for (int i = 0; i < PER; i++) {
    int idx = base + i;
    if (idx < M_) {
      int o = tp + pre[i];
      offs[idx] = o;
      cursor[idx] = o;
    }
  }
}

__global__ void scatter_k(const int* __restrict__ ei, int* __restrict__ cursor,
                          int2* __restrict__ rec)
{
  int i = blockIdx.x * 256 + threadIdx.x;
  if (i >= BE_) return;
  int b = i / E_, e = i - b * E_;
  int src = ei[(size_t)b * 2 * E_ + e];
  int trg = ei[(size_t)b * 2 * E_ + E_ + e];
  int pos = atomicAdd(&cursor[b * N_ + trg], 1);
  rec[pos] = make_int2(src, i);   // i = global edge id b*E+e
}

// ---------------------------------------------------------------------------
// Fused gather-aggregation: one wave per node, rec prefetch, NT rel loads.
// ---------------------------------------------------------------------------
__global__ __launch_bounds__(256)
void agg_k(const int2* __restrict__ rec, const int* __restrict__ offs,
           const int* __restrict__ cnt, const float* __restrict__ s_e,
           const unsigned* __restrict__ bmax,
           const float* __restrict__ proj, const float* __restrict__ rel,
           float* __restrict__ rel_agg, float* __restrict__ out_acc)
{
  int node = blockIdx.x * 4 + (threadIdx.x >> 6);
  if (node >= M_) return;
  int lane = threadIdx.x & 63;
  int b = node / N_;
  float m = dec_f(bmax[b]);
  int start = offs[node];
  int num   = cnt[node];
  int h = lane >> 3;

  f4 pacc = (f4)(0.f);
  f4 racc = (f4)(0.f);
  float dacc = 0.f;

  if (num > 0) {
    int2 cur = rec[start];
    for (int i = 0; i < num; i++) {
      int2 nxt = (i + 1 < num) ? rec[start + i + 1] : cur;
      float ex = expf(s_e[(size_t)cur.y * 8 + h] - m);
      f4 p  = *(const f4*)&proj[((size_t)b * N_ + cur.x) * FIN_ + lane * 4];
      f4 rv = __builtin_nontemporal_load(
                (const f4*)&rel[(size_t)cur.y * FIN_ + lane * 4]);
      dacc += ex;
      pacc += p * ex;
      racc += rv;
      cur = nxt;
    }
  }

  float inv = 1.f / (dacc + 1e-16f);
  pacc *= inv;
  *(f4*)&out_acc[(size_t)node * FIN_ + lane * 4] = pacc;
  *(f4*)&rel_agg[(size_t)node * FIN_ + lane * 4] = racc;
}

// ---------------------------------------------------------------------------
extern "C" void kernel_launch(void* const* d_in, const int* in_sizes, int n_in,
                              void* d_out, int out_size, void* d_ws, size_t ws_size,
                              hipStream_t stream)
{
  const float* x     = (const float*)d_in[0];
  const int*   ei    = (const int*)  d_in[1];
  const float* rel   = (const float*)d_in[2];
  const float* W     = (const float*)d_in[3];
  const float* a_src = (const float*)d_in[4];
  const float* a_trg = (const float*)d_in[5];
  const float* bias  = (const float*)d_in[6];
  float* out = (float*)d_out;

  float* ws = (float*)d_ws;
  size_t o = 0;
  float* proj    = ws + o; o += (size_t)M_ * FIN_;
  float* s_src   = ws + o; o += (size_t)M_ * H_;
  float* s_trg   = ws + o; o += (size_t)M_ * H_;
  float* s_e     = ws + o; o += (size_t)BE_ * H_;
  float* rel_agg = ws + o; o += (size_t)M_ * FIN_;
  float* out_acc = ws + o; o += (size_t)M_ * FIN_;
  int* cnt       = (int*)(ws + o);      o += M_;
  unsigned* bmax = (unsigned*)(ws + o); o += B_;
  int* offs      = (int*)(ws + o);      o += M_;
  int* cursor    = (int*)(ws + o);      o += M_;
  if (o & 1) o++;
  int2* rec      = (int2*)(ws + o);     o += (size_t)2 * BE_;

  // zero cnt + bmax (adjacent)
  hipMemsetAsync(cnt, 0, (M_ + B_) * sizeof(int), stream);

  gemm_k<0><<<dim3(313, 2), 256, 0, stream>>>(x, W, proj, nullptr, nullptr, nullptr);

  node_scores_k<<<(M_ * H_ + 255) / 256, 256, 0, stream>>>(proj, a_src, a_trg, s_src, s_trg);

  edge_scores_k<<<(BE_ + 255) / 256, 256, 0, stream>>>(ei, s_src, s_trg, s_e, bmax, cnt);

  scan_k<<<1, 1024, 0, stream>>>(cnt, offs, cursor);

  scatter_k<<<(BE_ + 255) / 256, 256, 0, stream>>>(ei, cursor, rec);

  agg_k<<<M_ / 4, 256, 0, stream>>>(rec, offs, cnt, s_e, bmax, proj, rel,
                                    rel_agg, out_acc);

  gemm_k<1><<<dim3(313, 2), 256, 0, stream>>>(rel_agg, W, out, out_acc, x, bias);
}